// Round 6
// baseline (357.116 us; speedup 1.0000x reference)
//
#include <hip/hip_runtime.h>
#include <stdint.h>

typedef unsigned short u16;
typedef __attribute__((ext_vector_type(4))) float f32x4;
typedef __attribute__((ext_vector_type(8))) short s16x8;

#define BATCH 4
#define SEQ   2048
#define DIM   1024   // D_IN = STATE = D_OUT
#define KX    10
#define PAD   16               // zero rows per batch for AR lags
#define SEQP  (SEQ+PAD)        // 2064

// fp32 -> bf16 round-to-nearest-even
__device__ __forceinline__ u16 f2b(float f) {
    union { float f; uint32_t u; } v; v.f = f;
    uint32_t u = v.u + 0x7fffu + ((v.u >> 16) & 1u);
    return (u16)(u >> 16);
}
__device__ __forceinline__ float b2f(u16 h) {
    union { uint32_t u; float f; } v; v.u = ((uint32_t)h) << 16;
    return v.f;
}

// async global->LDS, 16B per lane; lds dest is wave-uniform base (+lane*16 by HW)
__device__ __forceinline__ void llds16(const u16* g, u16* l) {
    __builtin_amdgcn_global_load_lds(
        (const __attribute__((address_space(1))) uint32_t*)g,
        (__attribute__((address_space(3))) uint32_t*)l, 16, 0, 0);
}

// ---------------- fused prep kernel ----------------
#define PREP_X_END  8256
#define PREP_C_END  10304
#define PREP_M_END  14400

__global__ __launch_bounds__(256) void k_prep(
    const float* __restrict__ x, const float* __restrict__ B,
    const float* __restrict__ C, const float* __restrict__ M,
    u16* __restrict__ Xpad, u16* __restrict__ Btr, u16* __restrict__ Wall)
{
    __shared__ float tile[32][33];
    const int bid = blockIdx.x, tid = threadIdx.x;

    if (bid < PREP_X_END) {
        // inputs (4,2048,1024) f32 -> Xpad (4,2064,1024) bf16, 16 zero rows/batch
        int idx = bid * 256 + tid;
        long e = (long)idx * 4;
        int i = (int)(e & 1023);
        int row = (int)(e >> 10);
        int t = row % SEQP;
        int b = row / SEQP;
        ushort4 o;
        if (t < PAD) {
            o.x = 0; o.y = 0; o.z = 0; o.w = 0;
        } else {
            const float4 v = *(const float4*)(x + (((long)(b * SEQ + (t - PAD)) << 10) + i));
            o.x = f2b(v.x); o.y = f2b(v.y); o.z = f2b(v.z); o.w = f2b(v.w);
        }
        *(ushort4*)(Xpad + ((long)row << 10) + i) = o;
    } else if (bid < PREP_C_END) {
        // transpose+bf16: B -> Btr, C -> Wall group 0
        const int tb = bid - PREP_X_END;
        const float* in = (tb < 1024) ? B : C;
        u16* out = (tb < 1024) ? Btr : Wall;
        int lb = tb & 1023;
        int bx = lb & 31, by = lb >> 5;
        int tx = tid & 31, ty = tid >> 5;
#pragma unroll
        for (int j = 0; j < 4; j++)
            tile[ty + j * 8][tx] = in[(long)(by * 32 + ty + j * 8) * 1024 + bx * 32 + tx];
        __syncthreads();
#pragma unroll
        for (int j = 0; j < 4; j++)
            out[(long)(bx * 32 + ty + j * 8) * 1024 + by * 32 + tx] = f2b(tile[tx][ty + j * 8]);
    } else {
        // M (o,i,k) f32 -> Wall groups 1..10 as [k][o][i] bf16
        int idx = (bid - PREP_C_END) * 256 + tid;
        int o = idx >> 10, i = idx & 1023;
        const float* src = M + (long)idx * KX;
#pragma unroll
        for (int k = 0; k < KX; k++)
            Wall[((long)(k + 1) << 20) + ((long)o << 10) + i] = f2b(src[k]);
    }
}

// ---------------- scan kernels (chunked parallel linear scan) ----------------

__global__ void k_scan1(const u16* __restrict__ U, const float* __restrict__ A,
                        float* __restrict__ F) {
    int s = blockIdx.x * 256 + threadIdx.x;
    int bc = blockIdx.y;
    int b = bc >> 4, c = bc & 15;
    float a = A[s];
    const u16* u = U + (((long)(b * SEQ + c * 128)) << 10) + s;
    float f = 0.f;
#pragma unroll 8
    for (int j = 0; j < 128; j++) f = fmaf(a, f, b2f(u[(long)j << 10]));
    F[((long)bc << 10) + s] = f;
}

__global__ void k_scan2(const float* __restrict__ F, const float* __restrict__ A,
                        const float* __restrict__ h0, float* __restrict__ Carry) {
    int idx = blockIdx.x * 256 + threadIdx.x;
    int b = idx >> 10, s = idx & 1023;
    float a = A[s];
    float a128 = a;
#pragma unroll
    for (int q = 0; q < 7; q++) a128 *= a128;
    float carry = h0[s];
#pragma unroll
    for (int c = 0; c < 16; c++) {
        long off = ((long)(b * 16 + c) << 10) + s;
        Carry[off] = carry;
        carry = fmaf(a128, carry, F[off]);
    }
}

// writes H in-place over U (same element, same thread -> no hazard)
__global__ void k_scan3(u16* __restrict__ U, const float* __restrict__ A,
                        const float* __restrict__ Carry) {
    int s = blockIdx.x * 256 + threadIdx.x;
    int bc = blockIdx.y;
    int b = bc >> 4, c = bc & 15;
    float a = A[s];
    long base = (((long)(b * SEQ + c * 128)) << 10) + s;
    float h = Carry[((long)bc << 10) + s];
#pragma unroll 8
    for (int j = 0; j < 128; j++) {
        h = fmaf(a, h, b2f(U[base + ((long)j << 10)]));
        U[base + ((long)j << 10)] = f2b(h);
    }
}

// ---------------- grouped GEMM: 128x64 tile, 4 waves, intra-block split-K ----------------
// out[r][n] = sum_g sum_k Aop_g[r][k] * W'[g][n][k]
// use_h=1 (11 groups): g in [0,9] -> A = Xpad rows lag g, W' = Wall group g+1 (M_g);
//                      g = 10    -> A = Hbf rows (lag 0), W' = Wall group 0 (C^T).
// use_h=0: g=0 -> A = Xpad lag 0, W' = W base (Btr).
// Split-K: waves {0,1} (pair 0) cover K[0,512), waves {2,3} (pair 1) K[512,1024),
// each pair with its own BK=32 X slab and W double-buffer. Identical control flow
// for all waves -> all __syncthreads align. LDS 36,864 B -> 4 blocks/CU; VGPR
// <=128 (launch_bounds 256,4) -> 16 waves/CU = 4 waves/SIMD: 2x the wave-TLP of
// the round-5 config at identical per-step work, swizzle class, and barrier count.
// Epilogue: pair 1 dumps acc to a 32KB f32 LDS scratch; pair 0 adds and stores.
// LDS map (u16 units): [0,5120) slabA, [5120,10240) slabB,
//                      [10240,18432) W bufs: pair*2+parity, 2048 u16 each.
__global__ __launch_bounds__(256, 4) void k_gemm(
    void* __restrict__ outv, const u16* __restrict__ Xpad,
    const u16* __restrict__ Hbf, const u16* __restrict__ W,
    int ngroups, int use_h, int bf16_out)
{
    __shared__ u16 smem[18432];          // 36,864 B

    const int tid  = threadIdx.x;
    const int wave = tid >> 6, lane = tid & 63;
    const int pair = wave >> 1, wm = wave & 1;      // pair: K-half; wm: row half
    const int quad = lane >> 4, l15 = lane & 15;

    const int col0 = blockIdx.x * 64;
    const int row0 = blockIdx.y * 128;
    const int bb = row0 >> 11;
    const long Xrow0 = (long)bb * SEQP + PAD + (row0 & (SEQ - 1));
    const long XslabBase = (Xrow0 - 16) << 10;
    const int lastg = ngroups - 1;

    f32x4 acc[4][4];
#pragma unroll
    for (int i = 0; i < 4; i++)
#pragma unroll
        for (int j = 0; j < 4; j++)
            acc[i][j] = (f32x4){0.f, 0.f, 0.f, 0.f};

    // ---- staging helpers (all 256 threads cooperate on both pairs) ----
    // X slab per pair: 160 rows x 32 k = 640 units of 16B (rows of 4 chunks,
    // chunk XOR-swizzled by row&3 on the global source; LDS written linearly)
    auto stageX2 = [&](int k0) {
#pragma unroll
        for (int p = 0; p < 2; p++) {
            const int kb = k0 + p * 512;
            u16* slab = smem + p * 5120;
#pragma unroll
            for (int q = 0; q < 2; q++) {
                int u = q * 256 + tid;
                int row = u >> 2;
                int kc = (u & 3) ^ (row & 3);
                llds16(Xpad + XslabBase + ((long)row << 10) + kb + kc * 8,
                       &slab[(q * 256 + wave * 64) * 8]);
            }
            {
                int u = 512 + tid;          // units 512..639, waves 0,1 only
                int row = u >> 2;
                int kc = (u & 3) ^ (row & 3);
                if (tid < 128)
                    llds16(Xpad + XslabBase + ((long)row << 10) + kb + kc * 8,
                           &slab[(512 + wave * 64) * 8]);
            }
        }
    };
    // W buffer per pair: 64 rows x 32 k = 256 units; one unit per thread per pair
    auto stageW2 = [&](int k0, int wsel, int parity) {
        const u16* Wg = W + ((long)wsel << 20) + ((long)col0 << 10);
#pragma unroll
        for (int p = 0; p < 2; p++) {
            int row = tid >> 2;
            int kc = (tid & 3) ^ (row & 3);
            llds16(Wg + ((long)row << 10) + (k0 + p * 512) + kc * 8,
                   &smem[10240 + (p * 2 + parity) * 2048 + wave * 64 * 8]);
        }
    };
    // H: 128 rows x 32 k = 512 units per pair, into slab rows [0,128)
    auto stageH2 = [&](int k0) {
        const u16* Hb = Hbf + ((long)row0 << 10);
#pragma unroll
        for (int p = 0; p < 2; p++) {
            const int kb = k0 + p * 512;
            u16* slab = smem + p * 5120;
#pragma unroll
            for (int q = 0; q < 2; q++) {
                int u = q * 256 + tid;
                int row = u >> 2;
                int kc = (u & 3) ^ (row & 3);
                llds16(Hb + ((long)row << 10) + kb + kc * 8,
                       &slab[(q * 256 + wave * 64) * 8]);
            }
        }
    };

    const u16* slab  = smem + pair * 5120;
    const u16* Wpair = smem + 10240 + pair * 2 * 2048;

    for (int k0 = 0; k0 < 512; k0 += 32) {
        // ---- stage X slabs (both pairs) + W for g=0 ----
        stageX2(k0);
        stageW2(k0, use_h ? 1 : 0, 0);
        __syncthreads();

        for (int g = 0; g < ngroups; g++) {
            const bool isH = use_h && (g == lastg);
            if (isH) {
                // previous barrier: slab reads done; overwrite rows [0,128) with H
                stageH2(k0);
                __syncthreads();
            }
            // ---- prefetch next W into the other parity (drained at end barrier) ----
            if (g < lastg) {
                int gn = g + 1;
                int wsel = use_h ? ((gn == lastg) ? 0 : gn + 1) : gn;
                stageW2(k0, wsel, gn & 1);
            }

            // ---- fragments (swizzled ds_read_b128), BK=32: one chunk per quad ----
            const int rbase = isH ? 0 : (16 - g);
            const u16* Wrd = Wpair + (g & 1) * 2048;

            s16x8 af[4], bfr[4];
#pragma unroll
            for (int mi = 0; mi < 4; mi++) {
                int arow = rbase + wm * 64 + mi * 16 + l15;
                int kca = (quad ^ (arow & 3)) << 3;
                af[mi] = *(const s16x8*)&slab[arow * 32 + kca];
            }
#pragma unroll
            for (int ni = 0; ni < 4; ni++) {
                int brow = ni * 16 + l15;
                int kcb = (quad ^ (brow & 3)) << 3;
                bfr[ni] = *(const s16x8*)&Wrd[brow * 32 + kcb];
            }
#pragma unroll
            for (int mi = 0; mi < 4; mi++)
#pragma unroll
                for (int ni = 0; ni < 4; ni++)
                    acc[mi][ni] = __builtin_amdgcn_mfma_f32_16x16x32_bf16(
                        af[mi], bfr[ni], acc[mi][ni], 0, 0, 0);
            __syncthreads();
        }
    }

    // ---- epilogue: combine K-halves via LDS scratch, then store ----
    // C/D layout col=lane&15, row=quad*4+reg
    float* scr = (float*)smem;           // 128 x 64 f32 = 32 KB
    if (pair == 1) {
#pragma unroll
        for (int mi = 0; mi < 4; mi++) {
            int rl = wm * 64 + mi * 16 + quad * 4;
#pragma unroll
            for (int ni = 0; ni < 4; ni++) {
                int c = ni * 16 + l15;
                f32x4 v = acc[mi][ni];
#pragma unroll
                for (int reg = 0; reg < 4; reg++)
                    scr[(rl + reg) * 64 + c] = v[reg];
            }
        }
    }
    __syncthreads();
    if (pair == 0) {
#pragma unroll
        for (int mi = 0; mi < 4; mi++) {
            int rl = wm * 64 + mi * 16 + quad * 4;
            int r = row0 + rl;
#pragma unroll
            for (int ni = 0; ni < 4; ni++) {
                int cl = ni * 16 + l15;
                int c = col0 + cl;
                f32x4 v = acc[mi][ni];
                if (bf16_out) {
                    u16* ob = (u16*)outv;
#pragma unroll
                    for (int reg = 0; reg < 4; reg++)
                        ob[((long)(r + reg) << 10) + c] =
                            f2b(v[reg] + scr[(rl + reg) * 64 + cl]);
                } else {
                    float* of = (float*)outv;
#pragma unroll
                    for (int reg = 0; reg < 4; reg++)
                        of[((long)(r + reg) << 10) + c] =
                            v[reg] + scr[(rl + reg) * 64 + cl];
                }
            }
        }
    }
}

// ---------------- launch ----------------

extern "C" void kernel_launch(void* const* d_in, const int* in_sizes, int n_in,
                              void* d_out, int out_size, void* d_ws, size_t ws_size,
                              hipStream_t stream) {
    const float* x  = (const float*)d_in[0];   // (4,2048,1024)
    const float* h0 = (const float*)d_in[1];   // (1024,)
    const float* A  = (const float*)d_in[2];   // (1024,)
    const float* B  = (const float*)d_in[3];   // (1024,1024)
    const float* C  = (const float*)d_in[4];   // (1024,1024)
    const float* M  = (const float*)d_in[5];   // (1024,1024,10)
    float* out = (float*)d_out;

    char* ws = (char*)d_ws;
    u16*   Xpad  = (u16*)  (ws);                      // 16,908,288
    u16*   Wall  = (u16*)  (ws + 16908288);           // 23,068,672 (group0 = C^T)
    u16*   Btr   = (u16*)  (ws + 39976960);           // 2,097,152
    u16*   Ubf   = (u16*)  (ws + 42074112);           // 16,777,216 (scan3 overwrites with H)
    float* F     = (float*)(ws + 58851328);           // 262,144
    float* Carry = (float*)(ws + 59113472);           // 262,144  (end ~59.4 MB)

    // fused conversions
    k_prep<<<dim3(PREP_M_END), dim3(256), 0, stream>>>(x, B, C, M, Xpad, Btr, Wall);

    // U = X @ B  (bf16 output)
    k_gemm<<<dim3(16, 64), dim3(256), 0, stream>>>(Ubf, Xpad, Ubf, Btr, 1, 0, 1);

    // chunked linear scan; scan3 turns Ubf into Hbf in-place
    k_scan1<<<dim3(4, 64), dim3(256), 0, stream>>>(Ubf, A, F);
    k_scan2<<<dim3(16), dim3(256), 0, stream>>>(F, A, h0, Carry);
    k_scan3<<<dim3(4, 64), dim3(256), 0, stream>>>(Ubf, A, Carry);

    // out = H @ C + sum_k shift_k(X) @ M_k   (11 K-groups)
    k_gemm<<<dim3(16, 64), dim3(256), 0, stream>>>(out, Xpad, Ubf, Wall, 11, 1, 0);
}

// Round 7
// 354.647 us; speedup vs baseline: 1.0070x; 1.0070x over previous
//
#include <hip/hip_runtime.h>
#include <stdint.h>

typedef unsigned short u16;
typedef __attribute__((ext_vector_type(4))) float f32x4;
typedef __attribute__((ext_vector_type(8))) short s16x8;

#define BATCH 4
#define SEQ   2048
#define DIM   1024   // D_IN = STATE = D_OUT
#define KX    10
#define PAD   16               // zero rows per batch for AR lags
#define SEQP  (SEQ+PAD)        // 2064

// fp32 -> bf16 round-to-nearest-even
__device__ __forceinline__ u16 f2b(float f) {
    union { float f; uint32_t u; } v; v.f = f;
    uint32_t u = v.u + 0x7fffu + ((v.u >> 16) & 1u);
    return (u16)(u >> 16);
}
__device__ __forceinline__ float b2f(u16 h) {
    union { uint32_t u; float f; } v; v.u = ((uint32_t)h) << 16;
    return v.f;
}

// async global->LDS, 16B per lane; lds dest is wave-uniform base (+lane*16 by HW)
__device__ __forceinline__ void llds16(const u16* g, u16* l) {
    __builtin_amdgcn_global_load_lds(
        (const __attribute__((address_space(1))) uint32_t*)g,
        (__attribute__((address_space(3))) uint32_t*)l, 16, 0, 0);
}

// ---------------- fused prep kernel ----------------
#define PREP_X_END  8256
#define PREP_C_END  10304
#define PREP_M_END  14400

__global__ __launch_bounds__(256) void k_prep(
    const float* __restrict__ x, const float* __restrict__ B,
    const float* __restrict__ C, const float* __restrict__ M,
    u16* __restrict__ Xpad, u16* __restrict__ Btr, u16* __restrict__ Wall)
{
    __shared__ float tile[32][33];
    const int bid = blockIdx.x, tid = threadIdx.x;

    if (bid < PREP_X_END) {
        // inputs (4,2048,1024) f32 -> Xpad (4,2064,1024) bf16, 16 zero rows/batch
        int idx = bid * 256 + tid;
        long e = (long)idx * 4;
        int i = (int)(e & 1023);
        int row = (int)(e >> 10);
        int t = row % SEQP;
        int b = row / SEQP;
        ushort4 o;
        if (t < PAD) {
            o.x = 0; o.y = 0; o.z = 0; o.w = 0;
        } else {
            const float4 v = *(const float4*)(x + (((long)(b * SEQ + (t - PAD)) << 10) + i));
            o.x = f2b(v.x); o.y = f2b(v.y); o.z = f2b(v.z); o.w = f2b(v.w);
        }
        *(ushort4*)(Xpad + ((long)row << 10) + i) = o;
    } else if (bid < PREP_C_END) {
        // transpose+bf16: B -> Btr, C -> Wall group 0
        const int tb = bid - PREP_X_END;
        const float* in = (tb < 1024) ? B : C;
        u16* out = (tb < 1024) ? Btr : Wall;
        int lb = tb & 1023;
        int bx = lb & 31, by = lb >> 5;
        int tx = tid & 31, ty = tid >> 5;
#pragma unroll
        for (int j = 0; j < 4; j++)
            tile[ty + j * 8][tx] = in[(long)(by * 32 + ty + j * 8) * 1024 + bx * 32 + tx];
        __syncthreads();
#pragma unroll
        for (int j = 0; j < 4; j++)
            out[(long)(bx * 32 + ty + j * 8) * 1024 + by * 32 + tx] = f2b(tile[tx][ty + j * 8]);
    } else {
        // M (o,i,k) f32 -> Wall groups 1..10 as [k][o][i] bf16
        int idx = (bid - PREP_C_END) * 256 + tid;
        int o = idx >> 10, i = idx & 1023;
        const float* src = M + (long)idx * KX;
#pragma unroll
        for (int k = 0; k < KX; k++)
            Wall[((long)(k + 1) << 20) + ((long)o << 10) + i] = f2b(src[k]);
    }
}

// ---------------- scan kernels (chunked parallel linear scan) ----------------
// 32 chunks of 64 rows per batch; bf16 columns processed 8-wide (short8 loads, G13).

__global__ void k_scan1(const u16* __restrict__ U, const float* __restrict__ A,
                        float* __restrict__ F) {
    const int sg = threadIdx.x;            // 0..127 -> cols [sg*8, sg*8+8)
    const int bc = blockIdx.x;             // 0..127: b = bc>>5, c = bc&31
    const int b = bc >> 5, c = bc & 31;
    const int s0 = sg << 3;
    const float4 a0 = *(const float4*)(A + s0);
    const float4 a1 = *(const float4*)(A + s0 + 4);
    float a[8] = {a0.x, a0.y, a0.z, a0.w, a1.x, a1.y, a1.z, a1.w};
    float f[8] = {0.f, 0.f, 0.f, 0.f, 0.f, 0.f, 0.f, 0.f};
    const u16* u = U + (((long)(b * SEQ + c * 64)) << 10) + s0;
#pragma unroll 4
    for (int j = 0; j < 64; j++) {
        s16x8 v = *(const s16x8*)(u + ((long)j << 10));
#pragma unroll
        for (int i = 0; i < 8; i++) f[i] = fmaf(a[i], f[i], b2f((u16)v[i]));
    }
    *(float4*)(F + ((long)bc << 10) + s0)     = (float4){f[0], f[1], f[2], f[3]};
    *(float4*)(F + ((long)bc << 10) + s0 + 4) = (float4){f[4], f[5], f[6], f[7]};
}

__global__ void k_scan2(const float* __restrict__ F, const float* __restrict__ A,
                        const float* __restrict__ h0, float* __restrict__ Carry) {
    int idx = blockIdx.x * 256 + threadIdx.x;
    int b = idx >> 10, s = idx & 1023;
    float a = A[s];
    float a64 = a;
#pragma unroll
    for (int q = 0; q < 6; q++) a64 *= a64;
    float carry = h0[s];
#pragma unroll
    for (int c = 0; c < 32; c++) {
        long off = ((long)(b * 32 + c) << 10) + s;
        Carry[off] = carry;
        carry = fmaf(a64, carry, F[off]);
    }
}

// writes H in-place over U (same element, same thread -> no hazard)
__global__ void k_scan3(u16* __restrict__ U, const float* __restrict__ A,
                        const float* __restrict__ Carry) {
    const int sg = threadIdx.x;
    const int bc = blockIdx.x;
    const int b = bc >> 5, c = bc & 31;
    const int s0 = sg << 3;
    const float4 a0 = *(const float4*)(A + s0);
    const float4 a1 = *(const float4*)(A + s0 + 4);
    float a[8] = {a0.x, a0.y, a0.z, a0.w, a1.x, a1.y, a1.z, a1.w};
    float h[8];
#pragma unroll
    for (int i = 0; i < 8; i++) h[i] = Carry[((long)bc << 10) + s0 + i];
    u16* u = U + (((long)(b * SEQ + c * 64)) << 10) + s0;
#pragma unroll 4
    for (int j = 0; j < 64; j++) {
        s16x8 v = *(const s16x8*)(u + ((long)j << 10));
        s16x8 w;
#pragma unroll
        for (int i = 0; i < 8; i++) {
            h[i] = fmaf(a[i], h[i], b2f((u16)v[i]));
            w[i] = (short)f2b(h[i]);
        }
        *(s16x8*)(u + ((long)j << 10)) = w;
    }
}

// ---------------- grouped GEMM: 128x64 tile, 4 waves, intra-block split-K ----------------
// out[r][n] = sum_g sum_k Aop_g[r][k] * W'[g][n][k]
// use_h=1 (11 groups): g in [0,9] -> A = Xpad rows lag g, W' = Wall group g+1 (M_g);
//                      g = 10    -> A = Hbf rows (lag 0), W' = Wall group 0 (C^T).
// use_h=0: g=0 -> A = Xpad lag 0, W' = W base (Btr).
// Split-K: waves {0,1} (pair 0) cover K[0,512), waves {2,3} (pair 1) K[512,1024),
// each pair with its own BK=32 X slab and W double-buffer. LDS 36,864 B -> 4
// blocks/CU, 16 waves/CU.
// BK=32 swizzle s(row) = (row>>1)&3 (NOT row&3): bank-slot = (row&1, quad^s(row));
// row&1 and (row>>1)&3 are independent over 16 consecutive rows -> all 8 slots x
// 2 lanes = conflict-free (round-6's row&3 correlated with row&1 -> 4-way, 2.4e7
// conflicts). Same involution pre-applied to the global source (rule 21).
// Epilogue: pair 1 dumps acc to a 32KB f32 LDS scratch; pair 0 adds and stores.
// LDS map (u16 units): [0,5120) slabA, [5120,10240) slabB,
//                      [10240,18432) W bufs: pair*2+parity, 2048 u16 each.
__global__ __launch_bounds__(256, 4) void k_gemm(
    void* __restrict__ outv, const u16* __restrict__ Xpad,
    const u16* __restrict__ Hbf, const u16* __restrict__ W,
    int ngroups, int use_h, int bf16_out)
{
    __shared__ u16 smem[18432];          // 36,864 B

    const int tid  = threadIdx.x;
    const int wave = tid >> 6, lane = tid & 63;
    const int pair = wave >> 1, wm = wave & 1;      // pair: K-half; wm: row half
    const int quad = lane >> 4, l15 = lane & 15;

    const int col0 = blockIdx.x * 64;
    const int row0 = blockIdx.y * 128;
    const int bb = row0 >> 11;
    const long Xrow0 = (long)bb * SEQP + PAD + (row0 & (SEQ - 1));
    const long XslabBase = (Xrow0 - 16) << 10;
    const int lastg = ngroups - 1;

    f32x4 acc[4][4];
#pragma unroll
    for (int i = 0; i < 4; i++)
#pragma unroll
        for (int j = 0; j < 4; j++)
            acc[i][j] = (f32x4){0.f, 0.f, 0.f, 0.f};

    // ---- staging helpers (all 256 threads cooperate on both pairs) ----
    // X slab per pair: 160 rows x 32 k = 640 units of 16B (4 chunks/row, source
    // chunk = slot ^ ((row>>1)&3); LDS written linearly)
    auto stageX2 = [&](int k0) {
#pragma unroll
        for (int p = 0; p < 2; p++) {
            const int kb = k0 + p * 512;
            u16* slab = smem + p * 5120;
#pragma unroll
            for (int q = 0; q < 2; q++) {
                int u = q * 256 + tid;
                int row = u >> 2;
                int kc = (u & 3) ^ ((row >> 1) & 3);
                llds16(Xpad + XslabBase + ((long)row << 10) + kb + kc * 8,
                       &slab[(q * 256 + wave * 64) * 8]);
            }
            {
                int u = 512 + tid;          // units 512..639, waves 0,1 only
                int row = u >> 2;
                int kc = (u & 3) ^ ((row >> 1) & 3);
                if (tid < 128)
                    llds16(Xpad + XslabBase + ((long)row << 10) + kb + kc * 8,
                           &slab[(512 + wave * 64) * 8]);
            }
        }
    };
    // W buffer per pair: 64 rows x 32 k = 256 units; one unit per thread per pair
    auto stageW2 = [&](int k0, int wsel, int parity) {
        const u16* Wg = W + ((long)wsel << 20) + ((long)col0 << 10);
#pragma unroll
        for (int p = 0; p < 2; p++) {
            int row = tid >> 2;
            int kc = (tid & 3) ^ ((row >> 1) & 3);
            llds16(Wg + ((long)row << 10) + (k0 + p * 512) + kc * 8,
                   &smem[10240 + (p * 2 + parity) * 2048 + wave * 64 * 8]);
        }
    };
    // H: 128 rows x 32 k = 512 units per pair, into slab rows [0,128)
    auto stageH2 = [&](int k0) {
        const u16* Hb = Hbf + ((long)row0 << 10);
#pragma unroll
        for (int p = 0; p < 2; p++) {
            const int kb = k0 + p * 512;
            u16* slab = smem + p * 5120;
#pragma unroll
            for (int q = 0; q < 2; q++) {
                int u = q * 256 + tid;
                int row = u >> 2;
                int kc = (u & 3) ^ ((row >> 1) & 3);
                llds16(Hb + ((long)row << 10) + kb + kc * 8,
                       &slab[(q * 256 + wave * 64) * 8]);
            }
        }
    };

    const u16* slab  = smem + pair * 5120;
    const u16* Wpair = smem + 10240 + pair * 2 * 2048;

    for (int k0 = 0; k0 < 512; k0 += 32) {
        // ---- stage X slabs (both pairs) + W for g=0 ----
        stageX2(k0);
        stageW2(k0, use_h ? 1 : 0, 0);
        __syncthreads();

        for (int g = 0; g < ngroups; g++) {
            const bool isH = use_h && (g == lastg);
            if (isH) {
                // previous barrier: slab reads done; overwrite rows [0,128) with H
                stageH2(k0);
                __syncthreads();
            }
            // ---- prefetch next W into the other parity (drained at end barrier) ----
            if (g < lastg) {
                int gn = g + 1;
                int wsel = use_h ? ((gn == lastg) ? 0 : gn + 1) : gn;
                stageW2(k0, wsel, gn & 1);
            }

            // ---- fragments (swizzled ds_read_b128), BK=32: one chunk per quad ----
            const int rbase = isH ? 0 : (16 - g);
            const u16* Wrd = Wpair + (g & 1) * 2048;

            s16x8 af[4], bfr[4];
#pragma unroll
            for (int mi = 0; mi < 4; mi++) {
                int arow = rbase + wm * 64 + mi * 16 + l15;
                int kca = (quad ^ ((arow >> 1) & 3)) << 3;
                af[mi] = *(const s16x8*)&slab[arow * 32 + kca];
            }
#pragma unroll
            for (int ni = 0; ni < 4; ni++) {
                int brow = ni * 16 + l15;
                int kcb = (quad ^ ((brow >> 1) & 3)) << 3;
                bfr[ni] = *(const s16x8*)&Wrd[brow * 32 + kcb];
            }
#pragma unroll
            for (int mi = 0; mi < 4; mi++)
#pragma unroll
                for (int ni = 0; ni < 4; ni++)
                    acc[mi][ni] = __builtin_amdgcn_mfma_f32_16x16x32_bf16(
                        af[mi], bfr[ni], acc[mi][ni], 0, 0, 0);
            __syncthreads();
        }
    }

    // ---- epilogue: combine K-halves via LDS scratch, then store ----
    // C/D layout col=lane&15, row=quad*4+reg
    float* scr = (float*)smem;           // 128 x 64 f32 = 32 KB
    if (pair == 1) {
#pragma unroll
        for (int mi = 0; mi < 4; mi++) {
            int rl = wm * 64 + mi * 16 + quad * 4;
#pragma unroll
            for (int ni = 0; ni < 4; ni++) {
                int c = ni * 16 + l15;
                f32x4 v = acc[mi][ni];
#pragma unroll
                for (int reg = 0; reg < 4; reg++)
                    scr[(rl + reg) * 64 + c] = v[reg];
            }
        }
    }
    __syncthreads();
    if (pair == 0) {
#pragma unroll
        for (int mi = 0; mi < 4; mi++) {
            int rl = wm * 64 + mi * 16 + quad * 4;
            int r = row0 + rl;
#pragma unroll
            for (int ni = 0; ni < 4; ni++) {
                int cl = ni * 16 + l15;
                int c = col0 + cl;
                f32x4 v = acc[mi][ni];
                if (bf16_out) {
                    u16* ob = (u16*)outv;
#pragma unroll
                    for (int reg = 0; reg < 4; reg++)
                        ob[((long)(r + reg) << 10) + c] =
                            f2b(v[reg] + scr[(rl + reg) * 64 + cl]);
                } else {
                    float* of = (float*)outv;
#pragma unroll
                    for (int reg = 0; reg < 4; reg++)
                        of[((long)(r + reg) << 10) + c] =
                            v[reg] + scr[(rl + reg) * 64 + cl];
                }
            }
        }
    }
}

// ---------------- launch ----------------

extern "C" void kernel_launch(void* const* d_in, const int* in_sizes, int n_in,
                              void* d_out, int out_size, void* d_ws, size_t ws_size,
                              hipStream_t stream) {
    const float* x  = (const float*)d_in[0];   // (4,2048,1024)
    const float* h0 = (const float*)d_in[1];   // (1024,)
    const float* A  = (const float*)d_in[2];   // (1024,)
    const float* B  = (const float*)d_in[3];   // (1024,1024)
    const float* C  = (const float*)d_in[4];   // (1024,1024)
    const float* M  = (const float*)d_in[5];   // (1024,1024,10)
    float* out = (float*)d_out;

    char* ws = (char*)d_ws;
    u16*   Xpad  = (u16*)  (ws);                      // 16,908,288
    u16*   Wall  = (u16*)  (ws + 16908288);           // 23,068,672 (group0 = C^T)
    u16*   Btr   = (u16*)  (ws + 39976960);           // 2,097,152
    u16*   Ubf   = (u16*)  (ws + 42074112);           // 16,777,216 (scan3 overwrites with H)
    // F/Carry (512 KB each) overlay the Btr region: Btr is dead after k_gemm(U);
    // scan1 writes F strictly after that (stream-ordered), and k_prep rewrites
    // Btr at the start of the next iteration.
    float* F     = (float*)(ws + 39976960);           // 524,288
    float* Carry = (float*)(ws + 39976960 + 524288);  // 524,288

    // fused conversions
    k_prep<<<dim3(PREP_M_END), dim3(256), 0, stream>>>(x, B, C, M, Xpad, Btr, Wall);

    // U = X @ B  (bf16 output)
    k_gemm<<<dim3(16, 64), dim3(256), 0, stream>>>(Ubf, Xpad, Ubf, Btr, 1, 0, 1);

    // chunked linear scan (32 chunks of 64); scan3 turns Ubf into Hbf in-place
    k_scan1<<<dim3(128), dim3(128), 0, stream>>>(Ubf, A, F);
    k_scan2<<<dim3(16), dim3(256), 0, stream>>>(F, A, h0, Carry);
    k_scan3<<<dim3(128), dim3(128), 0, stream>>>(Ubf, A, Carry);

    // out = H @ C + sum_k shift_k(X) @ M_k   (11 K-groups)
    k_gemm<<<dim3(16, 64), dim3(256), 0, stream>>>(out, Xpad, Ubf, Wall, 11, 1, 0);
}

// Round 8
// 346.947 us; speedup vs baseline: 1.0293x; 1.0222x over previous
//
#include <hip/hip_runtime.h>
#include <stdint.h>

typedef unsigned short u16;
typedef __attribute__((ext_vector_type(4))) float f32x4;
typedef __attribute__((ext_vector_type(8))) short s16x8;

#define BATCH 4
#define SEQ   2048
#define DIM   1024   // D_IN = STATE = D_OUT
#define KX    10
#define PAD   16               // zero rows per batch for AR lags
#define SEQP  (SEQ+PAD)        // 2064

// fp32 -> bf16 round-to-nearest-even
__device__ __forceinline__ u16 f2b(float f) {
    union { float f; uint32_t u; } v; v.f = f;
    uint32_t u = v.u + 0x7fffu + ((v.u >> 16) & 1u);
    return (u16)(u >> 16);
}
__device__ __forceinline__ float b2f(u16 h) {
    union { uint32_t u; float f; } v; v.u = ((uint32_t)h) << 16;
    return v.f;
}

// async global->LDS, 16B per lane; lds dest is wave-uniform base (+lane*16 by HW)
__device__ __forceinline__ void llds16(const u16* g, u16* l) {
    __builtin_amdgcn_global_load_lds(
        (const __attribute__((address_space(1))) uint32_t*)g,
        (__attribute__((address_space(3))) uint32_t*)l, 16, 0, 0);
}

// ---------------- fused prep kernel ----------------
#define PREP_X_END  8256
#define PREP_C_END  10304
#define PREP_M_END  14400

__global__ __launch_bounds__(256) void k_prep(
    const float* __restrict__ x, const float* __restrict__ B,
    const float* __restrict__ C, const float* __restrict__ M,
    u16* __restrict__ Xpad, u16* __restrict__ Btr, u16* __restrict__ Wall)
{
    __shared__ float tile[32][33];
    const int bid = blockIdx.x, tid = threadIdx.x;

    if (bid < PREP_X_END) {
        // inputs (4,2048,1024) f32 -> Xpad (4,2064,1024) bf16, 16 zero rows/batch
        int idx = bid * 256 + tid;
        long e = (long)idx * 4;
        int i = (int)(e & 1023);
        int row = (int)(e >> 10);
        int t = row % SEQP;
        int b = row / SEQP;
        ushort4 o;
        if (t < PAD) {
            o.x = 0; o.y = 0; o.z = 0; o.w = 0;
        } else {
            const float4 v = *(const float4*)(x + (((long)(b * SEQ + (t - PAD)) << 10) + i));
            o.x = f2b(v.x); o.y = f2b(v.y); o.z = f2b(v.z); o.w = f2b(v.w);
        }
        *(ushort4*)(Xpad + ((long)row << 10) + i) = o;
    } else if (bid < PREP_C_END) {
        // transpose+bf16: B -> Btr, C -> Wall group 0
        const int tb = bid - PREP_X_END;
        const float* in = (tb < 1024) ? B : C;
        u16* out = (tb < 1024) ? Btr : Wall;
        int lb = tb & 1023;
        int bx = lb & 31, by = lb >> 5;
        int tx = tid & 31, ty = tid >> 5;
#pragma unroll
        for (int j = 0; j < 4; j++)
            tile[ty + j * 8][tx] = in[(long)(by * 32 + ty + j * 8) * 1024 + bx * 32 + tx];
        __syncthreads();
#pragma unroll
        for (int j = 0; j < 4; j++)
            out[(long)(bx * 32 + ty + j * 8) * 1024 + by * 32 + tx] = f2b(tile[tx][ty + j * 8]);
    } else {
        // M (o,i,k) f32 -> Wall groups 1..10 as [k][o][i] bf16
        int idx = (bid - PREP_C_END) * 256 + tid;
        int o = idx >> 10, i = idx & 1023;
        const float* src = M + (long)idx * KX;
#pragma unroll
        for (int k = 0; k < KX; k++)
            Wall[((long)(k + 1) << 20) + ((long)o << 10) + i] = f2b(src[k]);
    }
}

// ---------------- scan kernels (chunked parallel linear scan) ----------------
// 64 chunks of 32 rows per batch; bf16 columns processed 8-wide (short8 loads, G13).

__global__ void k_scan1(const u16* __restrict__ U, const float* __restrict__ A,
                        float* __restrict__ F) {
    const int sg = threadIdx.x;            // 0..127 -> cols [sg*8, sg*8+8)
    const int bc = blockIdx.x;             // 0..255: b = bc>>6, c = bc&63
    const int b = bc >> 6, c = bc & 63;
    const int s0 = sg << 3;
    const float4 a0 = *(const float4*)(A + s0);
    const float4 a1 = *(const float4*)(A + s0 + 4);
    float a[8] = {a0.x, a0.y, a0.z, a0.w, a1.x, a1.y, a1.z, a1.w};
    float f[8] = {0.f, 0.f, 0.f, 0.f, 0.f, 0.f, 0.f, 0.f};
    const u16* u = U + (((long)(b * SEQ + c * 32)) << 10) + s0;
#pragma unroll 4
    for (int j = 0; j < 32; j++) {
        s16x8 v = *(const s16x8*)(u + ((long)j << 10));
#pragma unroll
        for (int i = 0; i < 8; i++) f[i] = fmaf(a[i], f[i], b2f((u16)v[i]));
    }
    *(float4*)(F + ((long)bc << 10) + s0)     = (float4){f[0], f[1], f[2], f[3]};
    *(float4*)(F + ((long)bc << 10) + s0 + 4) = (float4){f[4], f[5], f[6], f[7]};
}

__global__ void k_scan2(const float* __restrict__ F, const float* __restrict__ A,
                        const float* __restrict__ h0, float* __restrict__ Carry) {
    int idx = blockIdx.x * 256 + threadIdx.x;
    int b = idx >> 10, s = idx & 1023;
    float a = A[s];
    float a32 = a;
#pragma unroll
    for (int q = 0; q < 5; q++) a32 *= a32;
    float carry = h0[s];
#pragma unroll
    for (int c = 0; c < 64; c++) {
        long off = ((long)(b * 64 + c) << 10) + s;
        Carry[off] = carry;
        carry = fmaf(a32, carry, F[off]);
    }
}

// writes H in-place over U (same element, same thread -> no hazard)
__global__ void k_scan3(u16* __restrict__ U, const float* __restrict__ A,
                        const float* __restrict__ Carry) {
    const int sg = threadIdx.x;
    const int bc = blockIdx.x;
    const int b = bc >> 6, c = bc & 63;
    const int s0 = sg << 3;
    const float4 a0 = *(const float4*)(A + s0);
    const float4 a1 = *(const float4*)(A + s0 + 4);
    float a[8] = {a0.x, a0.y, a0.z, a0.w, a1.x, a1.y, a1.z, a1.w};
    float h[8];
#pragma unroll
    for (int i = 0; i < 8; i++) h[i] = Carry[((long)bc << 10) + s0 + i];
    u16* u = U + (((long)(b * SEQ + c * 32)) << 10) + s0;
#pragma unroll 4
    for (int j = 0; j < 32; j++) {
        s16x8 v = *(const s16x8*)(u + ((long)j << 10));
        s16x8 w;
#pragma unroll
        for (int i = 0; i < 8; i++) {
            h[i] = fmaf(a[i], h[i], b2f((u16)v[i]));
            w[i] = (short)f2b(h[i]);
        }
        *(s16x8*)(u + ((long)j << 10)) = w;
    }
}

// ---------------- grouped GEMM: 128x128 tile, 4 waves, split-K, 64x128/wave ----------------
// out[r][n] = sum_g sum_k Aop_g[r][k] * W'[g][n][k]
// use_h=1 (11 groups): g in [0,9] -> A = Xpad rows lag g, W' = Wall group g+1 (M_g);
//                      g = 10    -> A = Hbf rows (lag 0), W' = Wall group 0 (C^T).
// use_h=0: g=0 -> A = Xpad lag 0, W' = W base (Btr).
// Waves: wm = row-half (64 rows each), pair = K-half (K[0,512) / K[512,1024)),
// each pair with its own BK=32 X slab and W double-buffer. Per wave-step:
// 32 MFMA / 12 ds_read_b128 (r=2.67 vs round-7's r=2) -- per-MFMA overhead -40%.
// Swizzle (verified round 7, conflicts ~0): chunk = slot ^ ((row>>1)&3) on 64-B
// rows; same involution on global source and LDS read (rule 21).
// LDS 53,248 B -> 2 blocks/CU (grid 512 = exactly 2/CU); VGPR ~190 -> 2 waves/SIMD.
// Epilogue: pair 1 dumps acc to a padded f32 scratch in 2 halves; pair 0 adds+stores.
// LDS map (u16): [0,5120) slabA, [5120,10240) slabB,
//                [10240,26624) W bufs: (pair*2+parity)*4096, 128 cols x 32 k each.
__global__ __launch_bounds__(256, 2) void k_gemm(
    void* __restrict__ outv, const u16* __restrict__ Xpad,
    const u16* __restrict__ Hbf, const u16* __restrict__ W,
    int ngroups, int use_h, int bf16_out)
{
    __shared__ u16 smem[26624];          // 53,248 B

    const int tid  = threadIdx.x;
    const int wave = tid >> 6, lane = tid & 63;
    const int pair = wave >> 1, wm = wave & 1;      // pair: K-half; wm: row half
    const int quad = lane >> 4, l15 = lane & 15;

    const int col0 = blockIdx.x * 128;
    const int row0 = blockIdx.y * 128;
    const int bb = row0 >> 11;
    const long Xrow0 = (long)bb * SEQP + PAD + (row0 & (SEQ - 1));
    const long XslabBase = (Xrow0 - 16) << 10;
    const int lastg = ngroups - 1;

    f32x4 acc[4][8];
#pragma unroll
    for (int i = 0; i < 4; i++)
#pragma unroll
        for (int j = 0; j < 8; j++)
            acc[i][j] = (f32x4){0.f, 0.f, 0.f, 0.f};

    // ---- staging helpers (all 256 threads cooperate on both pairs) ----
    // X slab per pair: 160 rows x 32 k = 640 units of 16B
    auto stageX2 = [&](int k0) {
#pragma unroll
        for (int p = 0; p < 2; p++) {
            const int kb = k0 + p * 512;
            u16* slab = smem + p * 5120;
#pragma unroll
            for (int q = 0; q < 2; q++) {
                int u = q * 256 + tid;
                int row = u >> 2;
                int kc = (u & 3) ^ ((row >> 1) & 3);
                llds16(Xpad + XslabBase + ((long)row << 10) + kb + kc * 8,
                       &slab[(q * 256 + wave * 64) * 8]);
            }
            {
                int u = 512 + tid;          // units 512..639, waves 0,1 only
                int row = u >> 2;
                int kc = (u & 3) ^ ((row >> 1) & 3);
                if (tid < 128)
                    llds16(Xpad + XslabBase + ((long)row << 10) + kb + kc * 8,
                           &slab[(512 + wave * 64) * 8]);
            }
        }
    };
    // W buffer per pair: 128 rows x 32 k = 512 units; 2 units/thread/pair
    auto stageW2 = [&](int k0, int wsel, int parity) {
        const u16* Wg = W + ((long)wsel << 20) + ((long)col0 << 10);
#pragma unroll
        for (int p = 0; p < 2; p++) {
#pragma unroll
            for (int q = 0; q < 2; q++) {
                int u = q * 256 + tid;
                int row = u >> 2;
                int kc = (u & 3) ^ ((row >> 1) & 3);
                llds16(Wg + ((long)row << 10) + (k0 + p * 512) + kc * 8,
                       &smem[10240 + (p * 2 + parity) * 4096 + (q * 256 + wave * 64) * 8]);
            }
        }
    };
    // H: 128 rows x 32 k = 512 units per pair, into slab rows [0,128)
    auto stageH2 = [&](int k0) {
        const u16* Hb = Hbf + ((long)row0 << 10);
#pragma unroll
        for (int p = 0; p < 2; p++) {
            const int kb = k0 + p * 512;
            u16* slab = smem + p * 5120;
#pragma unroll
            for (int q = 0; q < 2; q++) {
                int u = q * 256 + tid;
                int row = u >> 2;
                int kc = (u & 3) ^ ((row >> 1) & 3);
                llds16(Hb + ((long)row << 10) + kb + kc * 8,
                       &slab[(q * 256 + wave * 64) * 8]);
            }
        }
    };

    const u16* slab  = smem + pair * 5120;
    const u16* Wpair = smem + 10240 + pair * 2 * 4096;

    for (int k0 = 0; k0 < 512; k0 += 32) {
        // ---- stage X slabs (both pairs) + W for g=0 ----
        stageX2(k0);
        stageW2(k0, use_h ? 1 : 0, 0);
        __syncthreads();

        for (int g = 0; g < ngroups; g++) {
            const bool isH = use_h && (g == lastg);
            if (isH) {
                // previous barrier: slab reads done; overwrite rows [0,128) with H
                stageH2(k0);
                __syncthreads();
            }
            // ---- prefetch next W into the other parity (drained at end barrier) ----
            if (g < lastg) {
                int gn = g + 1;
                int wsel = use_h ? ((gn == lastg) ? 0 : gn + 1) : gn;
                stageW2(k0, wsel, gn & 1);
            }

            // ---- fragments (swizzled ds_read_b128), BK=32: one chunk per quad ----
            const int rbase = isH ? 0 : (16 - g);
            const u16* Wrd = Wpair + (g & 1) * 4096;

            s16x8 bfr[8];
#pragma unroll
            for (int ni = 0; ni < 8; ni++) {
                int brow = ni * 16 + l15;
                int kcb = (quad ^ ((brow >> 1) & 3)) << 3;
                bfr[ni] = *(const s16x8*)&Wrd[brow * 32 + kcb];
            }
#pragma unroll
            for (int mi = 0; mi < 4; mi++) {
                int arow = rbase + wm * 64 + mi * 16 + l15;
                int kca = (quad ^ ((arow >> 1) & 3)) << 3;
                s16x8 af = *(const s16x8*)&slab[arow * 32 + kca];
#pragma unroll
                for (int ni = 0; ni < 8; ni++)
                    acc[mi][ni] = __builtin_amdgcn_mfma_f32_16x16x32_bf16(
                        af, bfr[ni], acc[mi][ni], 0, 0, 0);
            }
            __syncthreads();
        }
    }

    // ---- epilogue: combine K-halves via padded LDS scratch, 2 halves ----
    // C/D layout col=lane&15, row=quad*4+reg
    float* scr = (float*)smem;           // 64 x 129 f32 = 33,024 B <= 53,248
#pragma unroll
    for (int half = 0; half < 2; half++) {
        if (pair == 1) {
#pragma unroll
            for (int m2 = 0; m2 < 2; m2++) {
                int mi = half * 2 + m2;
                int rl = wm * 32 + m2 * 16 + quad * 4;
#pragma unroll
                for (int ni = 0; ni < 8; ni++) {
                    int c = ni * 16 + l15;
                    f32x4 v = acc[mi][ni];
#pragma unroll
                    for (int reg = 0; reg < 4; reg++)
                        scr[(rl + reg) * 129 + c] = v[reg];
                }
            }
        }
        __syncthreads();
        if (pair == 0) {
#pragma unroll
            for (int m2 = 0; m2 < 2; m2++) {
                int mi = half * 2 + m2;
                int rl = wm * 32 + m2 * 16 + quad * 4;
                int r = row0 + wm * 64 + mi * 16 + quad * 4;
#pragma unroll
                for (int ni = 0; ni < 8; ni++) {
                    int cl = ni * 16 + l15;
                    int c = col0 + cl;
                    f32x4 v = acc[mi][ni];
                    if (bf16_out) {
                        u16* ob = (u16*)outv;
#pragma unroll
                        for (int reg = 0; reg < 4; reg++)
                            ob[((long)(r + reg) << 10) + c] =
                                f2b(v[reg] + scr[(rl + reg) * 129 + cl]);
                    } else {
                        float* of = (float*)outv;
#pragma unroll
                        for (int reg = 0; reg < 4; reg++)
                            of[((long)(r + reg) << 10) + c] =
                                v[reg] + scr[(rl + reg) * 129 + cl];
                    }
                }
            }
        }
        __syncthreads();
    }
}

// ---------------- launch ----------------

extern "C" void kernel_launch(void* const* d_in, const int* in_sizes, int n_in,
                              void* d_out, int out_size, void* d_ws, size_t ws_size,
                              hipStream_t stream) {
    const float* x  = (const float*)d_in[0];   // (4,2048,1024)
    const float* h0 = (const float*)d_in[1];   // (1024,)
    const float* A  = (const float*)d_in[2];   // (1024,)
    const float* B  = (const float*)d_in[3];   // (1024,1024)
    const float* C  = (const float*)d_in[4];   // (1024,1024)
    const float* M  = (const float*)d_in[5];   // (1024,1024,10)
    float* out = (float*)d_out;

    char* ws = (char*)d_ws;
    u16*   Xpad  = (u16*)  (ws);                      // 16,908,288
    u16*   Wall  = (u16*)  (ws + 16908288);           // 23,068,672 (group0 = C^T)
    u16*   Btr   = (u16*)  (ws + 39976960);           // 2,097,152
    u16*   Ubf   = (u16*)  (ws + 42074112);           // 16,777,216 (scan3 overwrites with H)
    // F/Carry (1 MB each) overlay the Btr region: Btr is dead after k_gemm(U);
    // scan1 writes F strictly after that (stream-ordered), and k_prep rewrites
    // Btr at the start of the next iteration.
    float* F     = (float*)(ws + 39976960);           // 1,048,576
    float* Carry = (float*)(ws + 39976960 + 1048576); // 1,048,576

    // fused conversions
    k_prep<<<dim3(PREP_M_END), dim3(256), 0, stream>>>(x, B, C, M, Xpad, Btr, Wall);

    // U = X @ B  (bf16 output)
    k_gemm<<<dim3(8, 64), dim3(256), 0, stream>>>(Ubf, Xpad, Ubf, Btr, 1, 0, 1);

    // chunked linear scan (64 chunks of 32); scan3 turns Ubf into Hbf in-place
    k_scan1<<<dim3(256), dim3(128), 0, stream>>>(Ubf, A, F);
    k_scan2<<<dim3(16), dim3(256), 0, stream>>>(F, A, h0, Carry);
    k_scan3<<<dim3(256), dim3(128), 0, stream>>>(Ubf, A, Carry);

    // out = H @ C + sum_k shift_k(X) @ M_k   (11 K-groups)
    k_gemm<<<dim3(8, 64), dim3(256), 0, stream>>>(out, Xpad, Ubf, Wall, 11, 1, 0);
}